// Round 11
// baseline (252.966 us; speedup 1.0000x reference)
//
#include <hip/hip_runtime.h>
#include <hip/hip_bf16.h>
#include <cstdint>
#include <cstddef>

#define N_NODES 50000
#define NEG_SLOPE 0.2f
#define NB 196            // buckets of 256 nodes: (50000+255)/256
#define BIN_CHUNK 4096    // edges per block in hist/bin kernels (208 blocks)
#define SLICE_MAX 14336   // LDS slice capacity (mean ~4345, 3.3x headroom)

typedef float floatx4 __attribute__((ext_vector_type(4)));
typedef short shortx8 __attribute__((ext_vector_type(8)));

// ---- fp32 <-> bf16 helpers (RNE) --------------------------------------------
__device__ __forceinline__ unsigned short f2b(float f) {
    union { float f; unsigned u; } v; v.f = f;
    unsigned u = v.u;
    return (unsigned short)((u + 0x7FFFu + ((u >> 16) & 1u)) >> 16);
}
__device__ __forceinline__ float b2f(unsigned short b) {
    union { unsigned u; float f; } v; v.u = ((unsigned)b) << 16;
    return v.f;
}

// ---------------------------------------------------------------------------
// K1+K2 fused: per-block bucket histogram -> bhist_blk; the LAST finishing
// block (device-scope done counter, order-independent) sums the per-block
// hists, scans into bbase/bcursor, sets rowptr[N]=E. No global hist atomics.
// ---------------------------------------------------------------------------
__global__ __launch_bounds__(256) void bucket_hist_scan_kernel(
    const int* __restrict__ ei, int E0, int E,
    int* __restrict__ bhist_blk, int* __restrict__ done,
    int* __restrict__ bbase, int* __restrict__ bcursor,
    int* __restrict__ rowptr) {
    __shared__ int h[NB];
    __shared__ int buf[256];
    __shared__ int lastFlag;
    int t = threadIdx.x;
    for (int i = t; i < NB; i += 256) h[i] = 0;
    __syncthreads();
    int base = blockIdx.x * BIN_CHUNK;
    int end = min(base + BIN_CHUNK, E);
    for (int e = base + t; e < end; e += 256) {
        int d = (e < E0) ? ei[E0 + e] : (e - E0);
        atomicAdd(&h[d >> 8], 1);
    }
    __syncthreads();
    for (int i = t; i < NB; i += 256)
        bhist_blk[blockIdx.x * NB + i] = h[i];
    // publish, then check if we're the last block to finish
    __threadfence();
    if (t == 0) lastFlag = (atomicAdd(done, 1) == (int)gridDim.x - 1) ? 1 : 0;
    __syncthreads();
    if (!lastFlag) return;
    __threadfence();   // acquire: all bhist_blk writes visible
    int v = 0;
    if (t < NB)
        for (int blk = 0; blk < (int)gridDim.x; blk++)
            v += bhist_blk[blk * NB + t];
    int x = v;
    for (int off = 1; off < 256; off <<= 1) {
        buf[t] = x; __syncthreads();
        int y = (t >= off) ? buf[t - off] : 0;
        __syncthreads();
        x += y;
    }
    if (t < NB) {
        bbase[t] = x - v;      // exclusive
        bcursor[t] = x - v;
    }
    if (t == NB - 1) bbase[NB] = x;
    if (t == 0) rowptr[N_NODES] = E;
}

// K3: bin edges into bucket regions, packed src|(dst&255)<<16, burst writes.
// Local histogram comes pre-computed from K1 (bhist_blk) — no pass 1.
__global__ __launch_bounds__(256) void bin_kernel(
    const int* __restrict__ ei, int E0, int E,
    int* __restrict__ bcursor, unsigned int* __restrict__ ebuf,
    const int* __restrict__ bhist_blk) {
    __shared__ int h[NB];
    __shared__ int gbase[NB];
    int t = threadIdx.x;
    for (int i = t; i < NB; i += 256) {
        int c = bhist_blk[blockIdx.x * NB + i];
        gbase[i] = c ? atomicAdd(&bcursor[i], c) : 0;
        h[i] = 0;  // local cursor
    }
    __syncthreads();
    int base = blockIdx.x * BIN_CHUNK;
    int end = min(base + BIN_CHUNK, E);
    for (int e = base + t; e < end; e += 256) {
        int s, d;
        if (e < E0) { s = ei[e]; d = ei[E0 + e]; }
        else        { s = e - E0; d = e - E0; }
        int b = d >> 8;
        int off = atomicAdd(&h[b], 1);
        ebuf[gbase[b] + off] = (unsigned)s | ((unsigned)(d & 255) << 16);
    }
}

// K4: one block per bucket: local deg-hist -> rowptr, LDS-staged CSR slice.
__global__ __launch_bounds__(256) void build_kernel(
    const unsigned int* __restrict__ ebuf, const int* __restrict__ bbase,
    int* __restrict__ rowptr, int* __restrict__ csr_src) {
    __shared__ int h[256];
    __shared__ int lrp[257];
    __shared__ int stag[SLICE_MAX];
    int b = blockIdx.x, t = threadIdx.x;
    int e0 = bbase[b], e1 = bbase[b + 1];
    int cnt = e1 - e0;
    int n0 = b << 8;
    h[t] = 0;
    __syncthreads();
    for (int i = t; i < cnt; i += 256)
        atomicAdd(&h[ebuf[e0 + i] >> 16], 1);
    __syncthreads();
    int v = h[t], x = v;
    __shared__ int buf[256];
    for (int off = 1; off < 256; off <<= 1) {
        buf[t] = x; __syncthreads();
        int y = (t >= off) ? buf[t - off] : 0;
        __syncthreads();
        x += y;
    }
    lrp[t] = x - v;
    if (t == 255) lrp[256] = x;
    h[t] = 0;
    __syncthreads();
    int n = n0 + t;
    if (n < N_NODES) rowptr[n] = e0 + lrp[t];
    for (int i = t; i < cnt; i += 256) {
        unsigned int v2 = ebuf[e0 + i];
        int dloc = v2 >> 16;
        int off = atomicAdd(&h[dloc], 1);
        stag[lrp[dloc] + off] = (int)(v2 & 0xFFFFu);
    }
    __syncthreads();
    for (int i = t; i < cnt; i += 256) csr_src[e0 + i] = stag[i];
}

// ---------------------------------------------------------------------------
// Layer-1 GEMM (M=50000, N=128, K=256), B-stationary: stage half of W1 (bf16)
// in LDS once per half (2 stages, no per-K-step barriers); A streams
// global->reg->MFMA. 782 blocks x 4 waves run barrier-free inside each half.
// ---------------------------------------------------------------------------
#define G1_LDB 132   // B LDS row stride (elements): uniform bank spread
__global__ __launch_bounds__(256) void gemm1_att_kernel(
    const float* __restrict__ A, const float* __restrict__ B,
    const float* __restrict__ att_src, const float* __restrict__ att_dst,
    unsigned short* __restrict__ Cb, float* __restrict__ a_src,
    float* __restrict__ a_dst, int M) {
    __shared__ unsigned short smem[128 * G1_LDB];   // 33,792 B
    const int t = threadIdx.x;
    const int wave = t >> 6, lane = t & 63;
    const int lrow = lane & 15, lkg = lane >> 4;
    const int bm = blockIdx.x * 64;
    const int grow = bm + wave * 16 + lrow;
    const float* arow = A + (size_t)grow * 256;
    const bool rowok = grow < M;

    floatx4 acc[8] = {};

    for (int h = 0; h < 2; h++) {
        const int kbase = h * 128;
        if (h) __syncthreads();   // all reads of previous half done
#pragma unroll
        for (int q = 0; q < 16; q++) {
            int i = t + q * 256;
            int r = i >> 5, c4 = (i & 31) << 2;
            float4 v = *(const float4*)&B[(size_t)r * 256 + kbase + c4];
            ushort4 w;
            w.x = f2b(v.x); w.y = f2b(v.y); w.z = f2b(v.z); w.w = f2b(v.w);
            *(ushort4*)&smem[r * G1_LDB + c4] = w;
        }
        __syncthreads();
        float4 av0[2], av1[2], av2[2], av3[2];
        if (rowok) {
            int k0 = kbase + lkg * 8;
            av0[0] = *(const float4*)&arow[k0];      av0[1] = *(const float4*)&arow[k0 + 4];
            av1[0] = *(const float4*)&arow[k0 + 32]; av1[1] = *(const float4*)&arow[k0 + 36];
            av2[0] = *(const float4*)&arow[k0 + 64]; av2[1] = *(const float4*)&arow[k0 + 68];
            av3[0] = *(const float4*)&arow[k0 + 96]; av3[1] = *(const float4*)&arow[k0 + 100];
        } else {
            av0[0]=av0[1]=av1[0]=av1[1]=av2[0]=av2[1]=av3[0]=av3[1]=make_float4(0.f,0.f,0.f,0.f);
        }
#pragma unroll
        for (int s = 0; s < 4; s++) {
            float4 lo = (s==0)?av0[0]:(s==1)?av1[0]:(s==2)?av2[0]:av3[0];
            float4 hi = (s==0)?av0[1]:(s==1)?av1[1]:(s==2)?av2[1]:av3[1];
            shortx8 a;
            a[0]=(short)f2b(lo.x); a[1]=(short)f2b(lo.y);
            a[2]=(short)f2b(lo.z); a[3]=(short)f2b(lo.w);
            a[4]=(short)f2b(hi.x); a[5]=(short)f2b(hi.y);
            a[6]=(short)f2b(hi.z); a[7]=(short)f2b(hi.w);
            int kloc = s * 32 + lkg * 8;
#pragma unroll
            for (int nt = 0; nt < 8; nt++) {
                shortx8 b = *(const shortx8*)&smem[(nt * 16 + lrow) * G1_LDB + kloc];
                acc[nt] = __builtin_amdgcn_mfma_f32_16x16x32_bf16(a, b, acc[nt], 0, 0, 0);
            }
        }
    }

    __syncthreads();
    const int LDC = 136;
    unsigned short* Cs = smem;
#pragma unroll
    for (int nt = 0; nt < 8; nt++)
#pragma unroll
        for (int r = 0; r < 4; r++) {
            int row = wave * 16 + lkg * 4 + r;
            int col = nt * 16 + lrow;
            Cs[row * LDC + col] = f2b(acc[nt][r]);
        }
    __syncthreads();

#pragma unroll
    for (int q = 0; q < 4; q++) {
        int i = t + q * 256;
        int row = i >> 4, ch = i & 15;
        if (bm + row < M)
            *(shortx8*)&Cb[(size_t)(bm + row) * 128 + ch * 8] =
                *(const shortx8*)&Cs[row * LDC + ch * 8];
    }

    if (t < 128) {
        int row = t >> 1, which = t & 1;
        if (bm + row < M) {
            const float* av = which ? att_dst : att_src;
            float hs[4] = {0.f, 0.f, 0.f, 0.f};
#pragma unroll
            for (int c = 0; c < 16; c++) {
                float4 p = *(const float4*)&av[c * 8];
                float4 q2 = *(const float4*)&av[c * 8 + 4];
                shortx8 cv = *(const shortx8*)&Cs[row * LDC + c * 8];
                float s = b2f((unsigned short)cv[0]) * p.x
                        + b2f((unsigned short)cv[1]) * p.y
                        + b2f((unsigned short)cv[2]) * p.z
                        + b2f((unsigned short)cv[3]) * p.w
                        + b2f((unsigned short)cv[4]) * q2.x
                        + b2f((unsigned short)cv[5]) * q2.y
                        + b2f((unsigned short)cv[6]) * q2.z
                        + b2f((unsigned short)cv[7]) * q2.w;
                hs[c >> 2] += s;
            }
            float* outp = which ? a_dst : a_src;
#pragma unroll
            for (int hh = 0; hh < 4; hh++)
                outp[(size_t)(bm + row) * 4 + hh] = hs[hh];
        }
    }
}

// ---------------------------------------------------------------------------
// Layer-2 GEMM + att epilogue (round-6 verified code, unchanged).
// ---------------------------------------------------------------------------
template <int BM, int BN, int NREAL, int KK, int HEADS, typename InT>
__global__ __launch_bounds__(256) void gemm_att_kernel(
    const InT* __restrict__ A, const float* __restrict__ B,
    const float* __restrict__ att_src, const float* __restrict__ att_dst,
    unsigned short* __restrict__ Cb, float* __restrict__ a_src,
    float* __restrict__ a_dst, int M) {
    const int BK = 64, LDK = 72;
    const int NT = BN / 16;
    const int MT = BM / 64;
    const int NKI = KK / BK;
    const int LDC = NREAL + 8;
    const int NAs = BM * 8 / 256;
    const int NBv = BN * 16 / 256;
    constexpr int SMEM = ((BM + BN) * 72 > BM * (NREAL + 8)) ? (BM + BN) * 72
                                                             : BM * (NREAL + 8);
    __shared__ unsigned short smem[SMEM];
    unsigned short* As = smem;
    unsigned short* Bs = smem + BM * LDK;
    const int t = threadIdx.x;
    const int wave = t >> 6, lane = t & 63;
    const int lrow = lane & 15, lkg = lane >> 4;
    const int bm = blockIdx.x * BM;

    floatx4 acc[MT][NT] = {};
    shortx8 avs[NAs];
    float4 bv[NBv];

    {
        const int k0 = 0;
#pragma unroll
        for (int q = 0; q < NAs; q++) {
            int i = t + q * 256;
            int r = i >> 3, c8 = (i & 7) << 3;
            int gr = bm + r;
            shortx8 z = {};
            avs[q] = (gr < M) ? *(const shortx8*)&A[(size_t)gr * KK + k0 + c8] : z;
        }
#pragma unroll
        for (int q = 0; q < NBv; q++) {
            int i = t + q * 256;
            int r = i >> 4, c4 = (i & 15) << 2;
            bv[q] = (r < NREAL) ? *(const float4*)&B[(size_t)r * KK + k0 + c4]
                                : make_float4(0.f, 0.f, 0.f, 0.f);
        }
    }

    for (int ki = 0; ki < NKI; ki++) {
        __syncthreads();
#pragma unroll
        for (int q = 0; q < NAs; q++) {
            int i = t + q * 256;
            int r = i >> 3, c8 = (i & 7) << 3;
            *(shortx8*)&As[r * LDK + c8] = avs[q];
        }
#pragma unroll
        for (int q = 0; q < NBv; q++) {
            int i = t + q * 256;
            int r = i >> 4, c4 = (i & 15) << 2;
            int o = r * LDK + c4;
            float4 v = bv[q];
            Bs[o] = f2b(v.x); Bs[o + 1] = f2b(v.y);
            Bs[o + 2] = f2b(v.z); Bs[o + 3] = f2b(v.w);
        }
        if (ki + 1 < NKI) {
            const int k0 = (ki + 1) * BK;
#pragma unroll
            for (int q = 0; q < NAs; q++) {
                int i = t + q * 256;
                int r = i >> 3, c8 = (i & 7) << 3;
                int gr = bm + r;
                shortx8 z = {};
                avs[q] = (gr < M) ? *(const shortx8*)&A[(size_t)gr * KK + k0 + c8] : z;
            }
#pragma unroll
            for (int q = 0; q < NBv; q++) {
                int i = t + q * 256;
                int r = i >> 4, c4 = (i & 15) << 2;
                bv[q] = (r < NREAL) ? *(const float4*)&B[(size_t)r * KK + k0 + c4]
                                    : make_float4(0.f, 0.f, 0.f, 0.f);
            }
        }
        __syncthreads();
        for (int ks = 0; ks < BK; ks += 32) {
            int kc = ks + lkg * 8;
#pragma unroll
            for (int mt = 0; mt < MT; mt++) {
                int row = wave * (MT * 16) + mt * 16 + lrow;
                shortx8 a = *(const shortx8*)&As[row * LDK + kc];
#pragma unroll
                for (int nt = 0; nt < NT; nt++) {
                    shortx8 b = *(const shortx8*)&Bs[(nt * 16 + lrow) * LDK + kc];
                    acc[mt][nt] = __builtin_amdgcn_mfma_f32_16x16x32_bf16(a, b, acc[mt][nt], 0, 0, 0);
                }
            }
        }
    }

    __syncthreads();
    unsigned short* Cs = smem;
#pragma unroll
    for (int mt = 0; mt < MT; mt++)
#pragma unroll
        for (int nt = 0; nt < NT; nt++)
#pragma unroll
            for (int r = 0; r < 4; r++) {
                int row = wave * (MT * 16) + mt * 16 + lkg * 4 + r;
                int col = nt * 16 + lrow;
                if (col < NREAL) Cs[row * LDC + col] = f2b(acc[mt][nt][r]);
            }
    __syncthreads();

    const int NCH = NREAL / 8;
    for (int i = t; i < BM * NCH; i += 256) {
        int row = i / NCH, ch = i - row * NCH;
        if (bm + row < M)
            *(shortx8*)&Cb[(size_t)(bm + row) * NREAL + ch * 8] =
                *(const shortx8*)&Cs[row * LDC + ch * 8];
    }

    const int D = NREAL / HEADS;
    if (t < 2 * BM) {
        int row = t >> 1, which = t & 1;
        if (bm + row < M) {
            const float* av = which ? att_dst : att_src;
            float hs[HEADS];
#pragma unroll
            for (int h = 0; h < HEADS; h++) hs[h] = 0.f;
#pragma unroll
            for (int c = 0; c < NCH; c++) {
                float4 p = *(const float4*)&av[c * 8];
                float4 q = *(const float4*)&av[c * 8 + 4];
                shortx8 cv = *(const shortx8*)&Cs[row * LDC + c * 8];
                float s = b2f((unsigned short)cv[0]) * p.x
                        + b2f((unsigned short)cv[1]) * p.y
                        + b2f((unsigned short)cv[2]) * p.z
                        + b2f((unsigned short)cv[3]) * p.w
                        + b2f((unsigned short)cv[4]) * q.x
                        + b2f((unsigned short)cv[5]) * q.y
                        + b2f((unsigned short)cv[6]) * q.z
                        + b2f((unsigned short)cv[7]) * q.w;
                hs[(c * 8) / D] += s;
            }
            float* outp = which ? a_dst : a_src;
#pragma unroll
            for (int h = 0; h < HEADS; h++)
                outp[(size_t)(bm + row) * HEADS + h] = hs[h];
        }
    }
}

// ---------------------------------------------------------------------------
// Aggregation layer 1: one WAVE per node. dwordx4 gather (4 edges per
// wave-instruction) + 2-stage software pipeline across 16-edge chunks.
// ---------------------------------------------------------------------------
__global__ __launch_bounds__(256) void agg1_kernel(
    const unsigned short* __restrict__ h1b, const float* __restrict__ a_src,
    const float* __restrict__ a_dst, const int* __restrict__ rowptr,
    const int* __restrict__ csr_src, const float* __restrict__ b1,
    unsigned short* __restrict__ zb, int N) {
    int wave = threadIdx.x >> 6, lane = threadIdx.x & 63;
    int n = blockIdx.x * 4 + wave;
    if (n >= N) return;
    int eg = lane >> 4;
    int fpos = lane & 15;
    int hd = fpos >> 2;
    int lidx = lane >> 2;
    int lh = lane & 3;
    float adn = a_dst[n * 4 + lh];
    int beg = rowptr[n], deg = rowptr[n + 1] - beg;

    float acc[8] = {0.f, 0.f, 0.f, 0.f, 0.f, 0.f, 0.f, 0.f};
    float den = 0.f;

    int s_e = (lidx < deg) ? csr_src[beg + lidx] : 0;
    float asv = a_src[(s_e << 2) + lh];

    for (int c0 = 0; c0 < deg; c0 += 16) {
        float l = asv + adn;
        l = l > 0.f ? l : NEG_SLOPE * l;
        float w_e = (c0 + lidx < deg) ? __expf(l) : 0.f;
        int cnt = min(16, deg - c0);
        int s4[4]; float w4[4]; shortx8 v4[4];
#pragma unroll
        for (int q = 0; q < 4; q++) {
            int el = (q << 2) + eg;
            s4[q] = __shfl(s_e, el << 2);
            w4[q] = __shfl(w_e, (el << 2) + hd);
        }
#pragma unroll
        for (int q = 0; q < 4; q++) {
            if (q * 4 < cnt)
                v4[q] = *(const shortx8*)&h1b[(size_t)s4[q] * 128 + fpos * 8];
        }
        int nidx = c0 + 16 + lidx;
        int s_n = (nidx < deg) ? csr_src[beg + nidx] : 0;
        float asn = a_src[(s_n << 2) + lh];
#pragma unroll
        for (int q = 0; q < 4; q++) {
            if (q * 4 < cnt) {
                float w = w4[q];
                den += w;
#pragma unroll
                for (int j = 0; j < 8; j++)
                    acc[j] += w * b2f((unsigned short)v4[q][j]);
            }
        }
        s_e = s_n; asv = asn;
    }
#pragma unroll
    for (int j = 0; j < 8; j++) {
        acc[j] += __shfl_xor(acc[j], 16);
        acc[j] += __shfl_xor(acc[j], 32);
    }
    den += __shfl_xor(den, 16);
    den += __shfl_xor(den, 32);
    if (lane < 16) {
        float inv = 1.f / den;
        float4 bb0 = *(const float4*)&b1[fpos * 8];
        float4 bb1 = *(const float4*)&b1[fpos * 8 + 4];
        shortx8 r;
        r[0] = (short)f2b(fmaxf(acc[0] * inv + bb0.x, 0.f));
        r[1] = (short)f2b(fmaxf(acc[1] * inv + bb0.y, 0.f));
        r[2] = (short)f2b(fmaxf(acc[2] * inv + bb0.z, 0.f));
        r[3] = (short)f2b(fmaxf(acc[3] * inv + bb0.w, 0.f));
        r[4] = (short)f2b(fmaxf(acc[4] * inv + bb1.x, 0.f));
        r[5] = (short)f2b(fmaxf(acc[5] * inv + bb1.y, 0.f));
        r[6] = (short)f2b(fmaxf(acc[6] * inv + bb1.z, 0.f));
        r[7] = (short)f2b(fmaxf(acc[7] * inv + bb1.w, 0.f));
        *(shortx8*)&zb[(size_t)n * 128 + fpos * 8] = r;
    }
}

// ---------------------------------------------------------------------------
// Aggregation layer 2: one wave per node, H=1, D=40 (80B rows).
// ---------------------------------------------------------------------------
__global__ __launch_bounds__(256) void agg2_kernel(
    const unsigned short* __restrict__ h2b, const float* __restrict__ a_src,
    const float* __restrict__ a_dst, const int* __restrict__ rowptr,
    const int* __restrict__ csr_src, const float* __restrict__ b2,
    float* __restrict__ out, int N) {
    int wave = threadIdx.x >> 6, lane = threadIdx.x & 63;
    int n = blockIdx.x * 4 + wave;
    if (n >= N) return;
    int eg = (lane >= 40) ? 2 : (lane >= 20 ? 1 : 0);
    int fp = lane - eg * 20;
    bool act = fp < 20;
    float adn = a_dst[n];
    int beg = rowptr[n], deg = rowptr[n + 1] - beg;

    float2 acc = {0.f, 0.f};
    float den = 0.f;
    for (int c0 = 0; c0 < deg; c0 += 48) {
        int idx = c0 + lane;
        bool cv = (lane < 48) && (idx < deg);
        int s_e = cv ? csr_src[beg + idx] : 0;
        float l = a_src[s_e] + adn;
        l = l > 0.f ? l : NEG_SLOPE * l;
        float w_e = cv ? __expf(l) : 0.f;
        int cnt = min(48, deg - c0);
#pragma unroll
        for (int qq = 0; qq < 4; qq++) {
            if (qq * 12 < cnt) {
                int s4[4]; float w4[4]; ushort2 v4[4];
#pragma unroll
                for (int q = 0; q < 4; q++) {
                    int el = qq * 12 + q * 3 + eg;
                    s4[q] = __shfl(s_e, el);
                    w4[q] = __shfl(w_e, el);
                }
#pragma unroll
                for (int q = 0; q < 4; q++) {
                    if (act)
                        v4[q] = *(const ushort2*)&h2b[(size_t)s4[q] * 40 + fp * 2];
                }
#pragma unroll
                for (int q = 0; q < 4; q++) {
                    float w = w4[q];
                    den += w;
                    if (act) {
                        acc.x += w * b2f(v4[q].x);
                        acc.y += w * b2f(v4[q].y);
                    }
                }
            }
        }
    }
    float a1x = __shfl(acc.x, fp + 20), a2x = __shfl(acc.x, fp + 40);
    float a1y = __shfl(acc.y, fp + 20), a2y = __shfl(acc.y, fp + 40);
    float d1  = __shfl(den,  fp + 20), d2  = __shfl(den,  fp + 40);
    if (lane < 20) {
        float sx = acc.x + a1x + a2x;
        float sy = acc.y + a1y + a2y;
        float dtot = den + d1 + d2;
        float inv = 1.f / dtot;
        float2 bb = *(const float2*)&b2[fp * 2];
        float2 o;
        o.x = sx * inv + bb.x;
        o.y = sy * inv + bb.y;
        *(float2*)&out[(size_t)n * 40 + fp * 2] = o;
    }
}

// ---------------------------------------------------------------------------
extern "C" void kernel_launch(void* const* d_in, const int* in_sizes, int n_in,
                              void* d_out, int out_size, void* d_ws, size_t ws_size,
                              hipStream_t stream) {
    const float* x        = (const float*)d_in[0];
    const int*   ei       = (const int*)d_in[1];
    const float* W1       = (const float*)d_in[2];
    const float* att_src1 = (const float*)d_in[3];
    const float* att_dst1 = (const float*)d_in[4];
    const float* b1       = (const float*)d_in[5];
    const float* W2       = (const float*)d_in[6];
    const float* att_src2 = (const float*)d_in[7];
    const float* att_dst2 = (const float*)d_in[8];
    const float* b2       = (const float*)d_in[9];
    float* out = (float*)d_out;

    const int N  = N_NODES;
    const int E0 = in_sizes[1] / 2;
    const int E  = E0 + N;
    const int NBLK = (E + BIN_CHUNK - 1) / BIN_CHUNK;

    char* ws = (char*)d_ws;
    unsigned short* h1b = (unsigned short*)(ws + 0);          // 12,800,000
    unsigned short* zb  = (unsigned short*)(ws + 12800000);   // 12,800,000
    unsigned short* h2b = (unsigned short*)(ws + 25600000);   //  4,000,000
    float* a_src1 = (float*)(ws + 29600000);                  //    800,000
    float* a_dst1 = (float*)(ws + 30400000);                  //    800,000
    float* a_src2 = (float*)(ws + 31200000);                  //    200,000
    float* a_dst2 = (float*)(ws + 31400000);                  //    200,000
    int*   rowptr = (int*)(ws + 31600000);                    //    200,004
    int*   done   = (int*)(ws + 31800192);                    //          4
    int*   bbase  = (int*)(ws + 31801088);                    //        788
    int*   bcursor= (int*)(ws + 31801984);                    //        784
    unsigned int* ebuf = (unsigned int*)(ws + 31802880);      //  3,400,000
    int*   csr_src= (int*)(ws + 35202880);                    //  3,400,000
    int*   bhist_blk = (int*)(ws + 38602880);                 //   ~163,072
    // total ~38.8 MB

    hipMemsetAsync(done, 0, sizeof(int), stream);

    bucket_hist_scan_kernel<<<NBLK, 256, 0, stream>>>(
        ei, E0, E, bhist_blk, done, bbase, bcursor, rowptr);
    bin_kernel<<<NBLK, 256, 0, stream>>>(ei, E0, E, bcursor, ebuf, bhist_blk);
    build_kernel<<<NB, 256, 0, stream>>>(ebuf, bbase, rowptr, csr_src);

    // layer 1: h1b = bf16(x @ W1^T), fused a_src1/a_dst1 (B-stationary GEMM)
    gemm1_att_kernel<<<(N + 63) / 64, 256, 0, stream>>>(
        x, W1, att_src1, att_dst1, h1b, a_src1, a_dst1, N);
    agg1_kernel<<<(N + 3) / 4, 256, 0, stream>>>(h1b, a_src1, a_dst1, rowptr, csr_src, b1, zb, N);

    // layer 2: h2b = bf16(zb @ W2^T), fused a_src2/a_dst2
    gemm_att_kernel<64, 48, 40, 128, 1, unsigned short>
        <<<(N + 63) / 64, 256, 0, stream>>>(zb, W2, att_src2, att_dst2,
                                            h2b, a_src2, a_dst2, N);
    agg2_kernel<<<(N + 3) / 4, 256, 0, stream>>>(h2b, a_src2, a_dst2, rowptr, csr_src, b2, out, N);
}

// Round 12
// 233.173 us; speedup vs baseline: 1.0849x; 1.0849x over previous
//
#include <hip/hip_runtime.h>
#include <hip/hip_bf16.h>
#include <cstdint>
#include <cstddef>

#define N_NODES 50000
#define NEG_SLOPE 0.2f
#define NB 196            // buckets of 256 nodes: (50000+255)/256
#define BIN_CHUNK 8192    // edges per block in hist/bin kernels (104 blocks)
#define SLICE_MAX 14336   // LDS slice capacity (mean ~4345, 3.3x headroom)

typedef float floatx4 __attribute__((ext_vector_type(4)));
typedef short shortx8 __attribute__((ext_vector_type(8)));

// ---- fp32 <-> bf16 helpers (RNE) --------------------------------------------
__device__ __forceinline__ unsigned short f2b(float f) {
    union { float f; unsigned u; } v; v.f = f;
    unsigned u = v.u;
    return (unsigned short)((u + 0x7FFFu + ((u >> 16) & 1u)) >> 16);
}
__device__ __forceinline__ float b2f(unsigned short b) {
    union { unsigned u; float f; } v; v.u = ((unsigned)b) << 16;
    return v.f;
}

// ---------------------------------------------------------------------------
// K1+K2 fused: per-block bucket histogram -> bhist_blk; the LAST finishing
// block (device-scope done counter, order-independent) reduces + scans into
// bbase/bcursor, sets rowptr[N]=E. v2: reduction is 16-way load-batched
// (statically indexed regs) — round 11's serial tail was 208x~600cy = 50us;
// this is 7 batches x ~600cy = ~2us.
// ---------------------------------------------------------------------------
__global__ __launch_bounds__(256) void bucket_hist_scan_kernel(
    const int* __restrict__ ei, int E0, int E,
    int* __restrict__ bhist_blk, int* __restrict__ done,
    int* __restrict__ bbase, int* __restrict__ bcursor,
    int* __restrict__ rowptr) {
    __shared__ int h[NB];
    __shared__ int buf[256];
    __shared__ int lastFlag;
    int t = threadIdx.x;
    for (int i = t; i < NB; i += 256) h[i] = 0;
    __syncthreads();
    int base = blockIdx.x * BIN_CHUNK;
    int end = min(base + BIN_CHUNK, E);
    for (int e = base + t; e < end; e += 256) {
        int d = (e < E0) ? ei[E0 + e] : (e - E0);
        atomicAdd(&h[d >> 8], 1);
    }
    __syncthreads();
    for (int i = t; i < NB; i += 256)
        bhist_blk[blockIdx.x * NB + i] = h[i];
    // publish, then check if we're the last block to finish
    __threadfence();
    if (t == 0) lastFlag = (atomicAdd(done, 1) == (int)gridDim.x - 1) ? 1 : 0;
    __syncthreads();
    if (!lastFlag) return;
    __threadfence();   // acquire: all bhist_blk writes visible
    const int nblk = (int)gridDim.x;
    int v = 0;
    if (t < NB) {
        int blk = 0;
        for (; blk + 16 <= nblk; blk += 16) {
            int tmp[16];
#pragma unroll
            for (int j = 0; j < 16; j++)
                tmp[j] = bhist_blk[(blk + j) * NB + t];
#pragma unroll
            for (int j = 0; j < 16; j++) v += tmp[j];
        }
        for (; blk < nblk; blk++) v += bhist_blk[blk * NB + t];
    }
    int x = v;
    for (int off = 1; off < 256; off <<= 1) {
        buf[t] = x; __syncthreads();
        int y = (t >= off) ? buf[t - off] : 0;
        __syncthreads();
        x += y;
    }
    if (t < NB) {
        bbase[t] = x - v;      // exclusive
        bcursor[t] = x - v;
    }
    if (t == NB - 1) bbase[NB] = x;
    if (t == 0) rowptr[N_NODES] = E;
}

// K3: bin edges into bucket regions, packed src|(dst&255)<<16, burst writes.
// Local histogram comes pre-computed from K1 (bhist_blk) — no pass 1.
__global__ __launch_bounds__(256) void bin_kernel(
    const int* __restrict__ ei, int E0, int E,
    int* __restrict__ bcursor, unsigned int* __restrict__ ebuf,
    const int* __restrict__ bhist_blk) {
    __shared__ int h[NB];
    __shared__ int gbase[NB];
    int t = threadIdx.x;
    for (int i = t; i < NB; i += 256) {
        int c = bhist_blk[blockIdx.x * NB + i];
        gbase[i] = c ? atomicAdd(&bcursor[i], c) : 0;
        h[i] = 0;  // local cursor
    }
    __syncthreads();
    int base = blockIdx.x * BIN_CHUNK;
    int end = min(base + BIN_CHUNK, E);
    for (int e = base + t; e < end; e += 256) {
        int s, d;
        if (e < E0) { s = ei[e]; d = ei[E0 + e]; }
        else        { s = e - E0; d = e - E0; }
        int b = d >> 8;
        int off = atomicAdd(&h[b], 1);
        ebuf[gbase[b] + off] = (unsigned)s | ((unsigned)(d & 255) << 16);
    }
}

// K4: one block per bucket: local deg-hist -> rowptr, LDS-staged CSR slice.
__global__ __launch_bounds__(256) void build_kernel(
    const unsigned int* __restrict__ ebuf, const int* __restrict__ bbase,
    int* __restrict__ rowptr, int* __restrict__ csr_src) {
    __shared__ int h[256];
    __shared__ int lrp[257];
    __shared__ int stag[SLICE_MAX];
    int b = blockIdx.x, t = threadIdx.x;
    int e0 = bbase[b], e1 = bbase[b + 1];
    int cnt = e1 - e0;
    int n0 = b << 8;
    h[t] = 0;
    __syncthreads();
    for (int i = t; i < cnt; i += 256)
        atomicAdd(&h[ebuf[e0 + i] >> 16], 1);
    __syncthreads();
    int v = h[t], x = v;
    __shared__ int buf[256];
    for (int off = 1; off < 256; off <<= 1) {
        buf[t] = x; __syncthreads();
        int y = (t >= off) ? buf[t - off] : 0;
        __syncthreads();
        x += y;
    }
    lrp[t] = x - v;
    if (t == 255) lrp[256] = x;
    h[t] = 0;
    __syncthreads();
    int n = n0 + t;
    if (n < N_NODES) rowptr[n] = e0 + lrp[t];
    for (int i = t; i < cnt; i += 256) {
        unsigned int v2 = ebuf[e0 + i];
        int dloc = v2 >> 16;
        int off = atomicAdd(&h[dloc], 1);
        stag[lrp[dloc] + off] = (int)(v2 & 0xFFFFu);
    }
    __syncthreads();
    for (int i = t; i < cnt; i += 256) csr_src[e0 + i] = stag[i];
}

// ---------------------------------------------------------------------------
// Layer-1 GEMM (M=50000, N=128, K=256), B-stationary: stage half of W1 (bf16)
// in LDS once per half (2 stages, no per-K-step barriers); A streams
// global->reg->MFMA. 782 blocks x 4 waves run barrier-free inside each half.
// ---------------------------------------------------------------------------
#define G1_LDB 132   // B LDS row stride (elements): uniform bank spread
__global__ __launch_bounds__(256) void gemm1_att_kernel(
    const float* __restrict__ A, const float* __restrict__ B,
    const float* __restrict__ att_src, const float* __restrict__ att_dst,
    unsigned short* __restrict__ Cb, float* __restrict__ a_src,
    float* __restrict__ a_dst, int M) {
    __shared__ unsigned short smem[128 * G1_LDB];   // 33,792 B
    const int t = threadIdx.x;
    const int wave = t >> 6, lane = t & 63;
    const int lrow = lane & 15, lkg = lane >> 4;
    const int bm = blockIdx.x * 64;
    const int grow = bm + wave * 16 + lrow;
    const float* arow = A + (size_t)grow * 256;
    const bool rowok = grow < M;

    floatx4 acc[8] = {};

    for (int h = 0; h < 2; h++) {
        const int kbase = h * 128;
        if (h) __syncthreads();   // all reads of previous half done
#pragma unroll
        for (int q = 0; q < 16; q++) {
            int i = t + q * 256;
            int r = i >> 5, c4 = (i & 31) << 2;
            float4 v = *(const float4*)&B[(size_t)r * 256 + kbase + c4];
            ushort4 w;
            w.x = f2b(v.x); w.y = f2b(v.y); w.z = f2b(v.z); w.w = f2b(v.w);
            *(ushort4*)&smem[r * G1_LDB + c4] = w;
        }
        __syncthreads();
        float4 av0[2], av1[2], av2[2], av3[2];
        if (rowok) {
            int k0 = kbase + lkg * 8;
            av0[0] = *(const float4*)&arow[k0];      av0[1] = *(const float4*)&arow[k0 + 4];
            av1[0] = *(const float4*)&arow[k0 + 32]; av1[1] = *(const float4*)&arow[k0 + 36];
            av2[0] = *(const float4*)&arow[k0 + 64]; av2[1] = *(const float4*)&arow[k0 + 68];
            av3[0] = *(const float4*)&arow[k0 + 96]; av3[1] = *(const float4*)&arow[k0 + 100];
        } else {
            av0[0]=av0[1]=av1[0]=av1[1]=av2[0]=av2[1]=av3[0]=av3[1]=make_float4(0.f,0.f,0.f,0.f);
        }
#pragma unroll
        for (int s = 0; s < 4; s++) {
            float4 lo = (s==0)?av0[0]:(s==1)?av1[0]:(s==2)?av2[0]:av3[0];
            float4 hi = (s==0)?av0[1]:(s==1)?av1[1]:(s==2)?av2[1]:av3[1];
            shortx8 a;
            a[0]=(short)f2b(lo.x); a[1]=(short)f2b(lo.y);
            a[2]=(short)f2b(lo.z); a[3]=(short)f2b(lo.w);
            a[4]=(short)f2b(hi.x); a[5]=(short)f2b(hi.y);
            a[6]=(short)f2b(hi.z); a[7]=(short)f2b(hi.w);
            int kloc = s * 32 + lkg * 8;
#pragma unroll
            for (int nt = 0; nt < 8; nt++) {
                shortx8 b = *(const shortx8*)&smem[(nt * 16 + lrow) * G1_LDB + kloc];
                acc[nt] = __builtin_amdgcn_mfma_f32_16x16x32_bf16(a, b, acc[nt], 0, 0, 0);
            }
        }
    }

    __syncthreads();
    const int LDC = 136;
    unsigned short* Cs = smem;
#pragma unroll
    for (int nt = 0; nt < 8; nt++)
#pragma unroll
        for (int r = 0; r < 4; r++) {
            int row = wave * 16 + lkg * 4 + r;
            int col = nt * 16 + lrow;
            Cs[row * LDC + col] = f2b(acc[nt][r]);
        }
    __syncthreads();

#pragma unroll
    for (int q = 0; q < 4; q++) {
        int i = t + q * 256;
        int row = i >> 4, ch = i & 15;
        if (bm + row < M)
            *(shortx8*)&Cb[(size_t)(bm + row) * 128 + ch * 8] =
                *(const shortx8*)&Cs[row * LDC + ch * 8];
    }

    if (t < 128) {
        int row = t >> 1, which = t & 1;
        if (bm + row < M) {
            const float* av = which ? att_dst : att_src;
            float hs[4] = {0.f, 0.f, 0.f, 0.f};
#pragma unroll
            for (int c = 0; c < 16; c++) {
                float4 p = *(const float4*)&av[c * 8];
                float4 q2 = *(const float4*)&av[c * 8 + 4];
                shortx8 cv = *(const shortx8*)&Cs[row * LDC + c * 8];
                float s = b2f((unsigned short)cv[0]) * p.x
                        + b2f((unsigned short)cv[1]) * p.y
                        + b2f((unsigned short)cv[2]) * p.z
                        + b2f((unsigned short)cv[3]) * p.w
                        + b2f((unsigned short)cv[4]) * q2.x
                        + b2f((unsigned short)cv[5]) * q2.y
                        + b2f((unsigned short)cv[6]) * q2.z
                        + b2f((unsigned short)cv[7]) * q2.w;
                hs[c >> 2] += s;
            }
            float* outp = which ? a_dst : a_src;
#pragma unroll
            for (int hh = 0; hh < 4; hh++)
                outp[(size_t)(bm + row) * 4 + hh] = hs[hh];
        }
    }
}

// ---------------------------------------------------------------------------
// Layer-2 GEMM + att epilogue (round-6 verified code, unchanged).
// ---------------------------------------------------------------------------
template <int BM, int BN, int NREAL, int KK, int HEADS, typename InT>
__global__ __launch_bounds__(256) void gemm_att_kernel(
    const InT* __restrict__ A, const float* __restrict__ B,
    const float* __restrict__ att_src, const float* __restrict__ att_dst,
    unsigned short* __restrict__ Cb, float* __restrict__ a_src,
    float* __restrict__ a_dst, int M) {
    const int BK = 64, LDK = 72;
    const int NT = BN / 16;
    const int MT = BM / 64;
    const int NKI = KK / BK;
    const int LDC = NREAL + 8;
    const int NAs = BM * 8 / 256;
    const int NBv = BN * 16 / 256;
    constexpr int SMEM = ((BM + BN) * 72 > BM * (NREAL + 8)) ? (BM + BN) * 72
                                                             : BM * (NREAL + 8);
    __shared__ unsigned short smem[SMEM];
    unsigned short* As = smem;
    unsigned short* Bs = smem + BM * LDK;
    const int t = threadIdx.x;
    const int wave = t >> 6, lane = t & 63;
    const int lrow = lane & 15, lkg = lane >> 4;
    const int bm = blockIdx.x * BM;

    floatx4 acc[MT][NT] = {};
    shortx8 avs[NAs];
    float4 bv[NBv];

    {
        const int k0 = 0;
#pragma unroll
        for (int q = 0; q < NAs; q++) {
            int i = t + q * 256;
            int r = i >> 3, c8 = (i & 7) << 3;
            int gr = bm + r;
            shortx8 z = {};
            avs[q] = (gr < M) ? *(const shortx8*)&A[(size_t)gr * KK + k0 + c8] : z;
        }
#pragma unroll
        for (int q = 0; q < NBv; q++) {
            int i = t + q * 256;
            int r = i >> 4, c4 = (i & 15) << 2;
            bv[q] = (r < NREAL) ? *(const float4*)&B[(size_t)r * KK + k0 + c4]
                                : make_float4(0.f, 0.f, 0.f, 0.f);
        }
    }

    for (int ki = 0; ki < NKI; ki++) {
        __syncthreads();
#pragma unroll
        for (int q = 0; q < NAs; q++) {
            int i = t + q * 256;
            int r = i >> 3, c8 = (i & 7) << 3;
            *(shortx8*)&As[r * LDK + c8] = avs[q];
        }
#pragma unroll
        for (int q = 0; q < NBv; q++) {
            int i = t + q * 256;
            int r = i >> 4, c4 = (i & 15) << 2;
            int o = r * LDK + c4;
            float4 v = bv[q];
            Bs[o] = f2b(v.x); Bs[o + 1] = f2b(v.y);
            Bs[o + 2] = f2b(v.z); Bs[o + 3] = f2b(v.w);
        }
        if (ki + 1 < NKI) {
            const int k0 = (ki + 1) * BK;
#pragma unroll
            for (int q = 0; q < NAs; q++) {
                int i = t + q * 256;
                int r = i >> 3, c8 = (i & 7) << 3;
                int gr = bm + r;
                shortx8 z = {};
                avs[q] = (gr < M) ? *(const shortx8*)&A[(size_t)gr * KK + k0 + c8] : z;
            }
#pragma unroll
            for (int q = 0; q < NBv; q++) {
                int i = t + q * 256;
                int r = i >> 4, c4 = (i & 15) << 2;
                bv[q] = (r < NREAL) ? *(const float4*)&B[(size_t)r * KK + k0 + c4]
                                    : make_float4(0.f, 0.f, 0.f, 0.f);
            }
        }
        __syncthreads();
        for (int ks = 0; ks < BK; ks += 32) {
            int kc = ks + lkg * 8;
#pragma unroll
            for (int mt = 0; mt < MT; mt++) {
                int row = wave * (MT * 16) + mt * 16 + lrow;
                shortx8 a = *(const shortx8*)&As[row * LDK + kc];
#pragma unroll
                for (int nt = 0; nt < NT; nt++) {
                    shortx8 b = *(const shortx8*)&Bs[(nt * 16 + lrow) * LDK + kc];
                    acc[mt][nt] = __builtin_amdgcn_mfma_f32_16x16x32_bf16(a, b, acc[mt][nt], 0, 0, 0);
                }
            }
        }
    }

    __syncthreads();
    unsigned short* Cs = smem;
#pragma unroll
    for (int mt = 0; mt < MT; mt++)
#pragma unroll
        for (int nt = 0; nt < NT; nt++)
#pragma unroll
            for (int r = 0; r < 4; r++) {
                int row = wave * (MT * 16) + mt * 16 + lkg * 4 + r;
                int col = nt * 16 + lrow;
                if (col < NREAL) Cs[row * LDC + col] = f2b(acc[mt][nt][r]);
            }
    __syncthreads();

    const int NCH = NREAL / 8;
    for (int i = t; i < BM * NCH; i += 256) {
        int row = i / NCH, ch = i - row * NCH;
        if (bm + row < M)
            *(shortx8*)&Cb[(size_t)(bm + row) * NREAL + ch * 8] =
                *(const shortx8*)&Cs[row * LDC + ch * 8];
    }

    const int D = NREAL / HEADS;
    if (t < 2 * BM) {
        int row = t >> 1, which = t & 1;
        if (bm + row < M) {
            const float* av = which ? att_dst : att_src;
            float hs[HEADS];
#pragma unroll
            for (int h = 0; h < HEADS; h++) hs[h] = 0.f;
#pragma unroll
            for (int c = 0; c < NCH; c++) {
                float4 p = *(const float4*)&av[c * 8];
                float4 q = *(const float4*)&av[c * 8 + 4];
                shortx8 cv = *(const shortx8*)&Cs[row * LDC + c * 8];
                float s = b2f((unsigned short)cv[0]) * p.x
                        + b2f((unsigned short)cv[1]) * p.y
                        + b2f((unsigned short)cv[2]) * p.z
                        + b2f((unsigned short)cv[3]) * p.w
                        + b2f((unsigned short)cv[4]) * q.x
                        + b2f((unsigned short)cv[5]) * q.y
                        + b2f((unsigned short)cv[6]) * q.z
                        + b2f((unsigned short)cv[7]) * q.w;
                hs[(c * 8) / D] += s;
            }
            float* outp = which ? a_dst : a_src;
#pragma unroll
            for (int h = 0; h < HEADS; h++)
                outp[(size_t)(bm + row) * HEADS + h] = hs[h];
        }
    }
}

// ---------------------------------------------------------------------------
// Aggregation layer 1: one WAVE per node. dwordx4 gather (4 edges per
// wave-instruction) + 2-stage software pipeline across 16-edge chunks.
// ---------------------------------------------------------------------------
__global__ __launch_bounds__(256) void agg1_kernel(
    const unsigned short* __restrict__ h1b, const float* __restrict__ a_src,
    const float* __restrict__ a_dst, const int* __restrict__ rowptr,
    const int* __restrict__ csr_src, const float* __restrict__ b1,
    unsigned short* __restrict__ zb, int N) {
    int wave = threadIdx.x >> 6, lane = threadIdx.x & 63;
    int n = blockIdx.x * 4 + wave;
    if (n >= N) return;
    int eg = lane >> 4;
    int fpos = lane & 15;
    int hd = fpos >> 2;
    int lidx = lane >> 2;
    int lh = lane & 3;
    float adn = a_dst[n * 4 + lh];
    int beg = rowptr[n], deg = rowptr[n + 1] - beg;

    float acc[8] = {0.f, 0.f, 0.f, 0.f, 0.f, 0.f, 0.f, 0.f};
    float den = 0.f;

    int s_e = (lidx < deg) ? csr_src[beg + lidx] : 0;
    float asv = a_src[(s_e << 2) + lh];

    for (int c0 = 0; c0 < deg; c0 += 16) {
        float l = asv + adn;
        l = l > 0.f ? l : NEG_SLOPE * l;
        float w_e = (c0 + lidx < deg) ? __expf(l) : 0.f;
        int cnt = min(16, deg - c0);
        int s4[4]; float w4[4]; shortx8 v4[4];
#pragma unroll
        for (int q = 0; q < 4; q++) {
            int el = (q << 2) + eg;
            s4[q] = __shfl(s_e, el << 2);
            w4[q] = __shfl(w_e, (el << 2) + hd);
        }
#pragma unroll
        for (int q = 0; q < 4; q++) {
            if (q * 4 < cnt)
                v4[q] = *(const shortx8*)&h1b[(size_t)s4[q] * 128 + fpos * 8];
        }
        int nidx = c0 + 16 + lidx;
        int s_n = (nidx < deg) ? csr_src[beg + nidx] : 0;
        float asn = a_src[(s_n << 2) + lh];
#pragma unroll
        for (int q = 0; q < 4; q++) {
            if (q * 4 < cnt) {
                float w = w4[q];
                den += w;
#pragma unroll
                for (int j = 0; j < 8; j++)
                    acc[j] += w * b2f((unsigned short)v4[q][j]);
            }
        }
        s_e = s_n; asv = asn;
    }
#pragma unroll
    for (int j = 0; j < 8; j++) {
        acc[j] += __shfl_xor(acc[j], 16);
        acc[j] += __shfl_xor(acc[j], 32);
    }
    den += __shfl_xor(den, 16);
    den += __shfl_xor(den, 32);
    if (lane < 16) {
        float inv = 1.f / den;
        float4 bb0 = *(const float4*)&b1[fpos * 8];
        float4 bb1 = *(const float4*)&b1[fpos * 8 + 4];
        shortx8 r;
        r[0] = (short)f2b(fmaxf(acc[0] * inv + bb0.x, 0.f));
        r[1] = (short)f2b(fmaxf(acc[1] * inv + bb0.y, 0.f));
        r[2] = (short)f2b(fmaxf(acc[2] * inv + bb0.z, 0.f));
        r[3] = (short)f2b(fmaxf(acc[3] * inv + bb0.w, 0.f));
        r[4] = (short)f2b(fmaxf(acc[4] * inv + bb1.x, 0.f));
        r[5] = (short)f2b(fmaxf(acc[5] * inv + bb1.y, 0.f));
        r[6] = (short)f2b(fmaxf(acc[6] * inv + bb1.z, 0.f));
        r[7] = (short)f2b(fmaxf(acc[7] * inv + bb1.w, 0.f));
        *(shortx8*)&zb[(size_t)n * 128 + fpos * 8] = r;
    }
}

// ---------------------------------------------------------------------------
// Aggregation layer 2: one wave per node, H=1, D=40 (80B rows).
// ---------------------------------------------------------------------------
__global__ __launch_bounds__(256) void agg2_kernel(
    const unsigned short* __restrict__ h2b, const float* __restrict__ a_src,
    const float* __restrict__ a_dst, const int* __restrict__ rowptr,
    const int* __restrict__ csr_src, const float* __restrict__ b2,
    float* __restrict__ out, int N) {
    int wave = threadIdx.x >> 6, lane = threadIdx.x & 63;
    int n = blockIdx.x * 4 + wave;
    if (n >= N) return;
    int eg = (lane >= 40) ? 2 : (lane >= 20 ? 1 : 0);
    int fp = lane - eg * 20;
    bool act = fp < 20;
    float adn = a_dst[n];
    int beg = rowptr[n], deg = rowptr[n + 1] - beg;

    float2 acc = {0.f, 0.f};
    float den = 0.f;
    for (int c0 = 0; c0 < deg; c0 += 48) {
        int idx = c0 + lane;
        bool cv = (lane < 48) && (idx < deg);
        int s_e = cv ? csr_src[beg + idx] : 0;
        float l = a_src[s_e] + adn;
        l = l > 0.f ? l : NEG_SLOPE * l;
        float w_e = cv ? __expf(l) : 0.f;
        int cnt = min(48, deg - c0);
#pragma unroll
        for (int qq = 0; qq < 4; qq++) {
            if (qq * 12 < cnt) {
                int s4[4]; float w4[4]; ushort2 v4[4];
#pragma unroll
                for (int q = 0; q < 4; q++) {
                    int el = qq * 12 + q * 3 + eg;
                    s4[q] = __shfl(s_e, el);
                    w4[q] = __shfl(w_e, el);
                }
#pragma unroll
                for (int q = 0; q < 4; q++) {
                    if (act)
                        v4[q] = *(const ushort2*)&h2b[(size_t)s4[q] * 40 + fp * 2];
                }
#pragma unroll
                for (int q = 0; q < 4; q++) {
                    float w = w4[q];
                    den += w;
                    if (act) {
                        acc.x += w * b2f(v4[q].x);
                        acc.y += w * b2f(v4[q].y);
                    }
                }
            }
        }
    }
    float a1x = __shfl(acc.x, fp + 20), a2x = __shfl(acc.x, fp + 40);
    float a1y = __shfl(acc.y, fp + 20), a2y = __shfl(acc.y, fp + 40);
    float d1  = __shfl(den,  fp + 20), d2  = __shfl(den,  fp + 40);
    if (lane < 20) {
        float sx = acc.x + a1x + a2x;
        float sy = acc.y + a1y + a2y;
        float dtot = den + d1 + d2;
        float inv = 1.f / dtot;
        float2 bb = *(const float2*)&b2[fp * 2];
        float2 o;
        o.x = sx * inv + bb.x;
        o.y = sy * inv + bb.y;
        *(float2*)&out[(size_t)n * 40 + fp * 2] = o;
    }
}

// ---------------------------------------------------------------------------
extern "C" void kernel_launch(void* const* d_in, const int* in_sizes, int n_in,
                              void* d_out, int out_size, void* d_ws, size_t ws_size,
                              hipStream_t stream) {
    const float* x        = (const float*)d_in[0];
    const int*   ei       = (const int*)d_in[1];
    const float* W1       = (const float*)d_in[2];
    const float* att_src1 = (const float*)d_in[3];
    const float* att_dst1 = (const float*)d_in[4];
    const float* b1       = (const float*)d_in[5];
    const float* W2       = (const float*)d_in[6];
    const float* att_src2 = (const float*)d_in[7];
    const float* att_dst2 = (const float*)d_in[8];
    const float* b2       = (const float*)d_in[9];
    float* out = (float*)d_out;

    const int N  = N_NODES;
    const int E0 = in_sizes[1] / 2;
    const int E  = E0 + N;
    const int NBLK = (E + BIN_CHUNK - 1) / BIN_CHUNK;

    char* ws = (char*)d_ws;
    unsigned short* h1b = (unsigned short*)(ws + 0);          // 12,800,000
    unsigned short* zb  = (unsigned short*)(ws + 12800000);   // 12,800,000
    unsigned short* h2b = (unsigned short*)(ws + 25600000);   //  4,000,000
    float* a_src1 = (float*)(ws + 29600000);                  //    800,000
    float* a_dst1 = (float*)(ws + 30400000);                  //    800,000
    float* a_src2 = (float*)(ws + 31200000);                  //    200,000
    float* a_dst2 = (float*)(ws + 31400000);                  //    200,000
    int*   rowptr = (int*)(ws + 31600000);                    //    200,004
    int*   done   = (int*)(ws + 31800192);                    //          4
    int*   bbase  = (int*)(ws + 31801088);                    //        788
    int*   bcursor= (int*)(ws + 31801984);                    //        784
    unsigned int* ebuf = (unsigned int*)(ws + 31802880);      //  3,400,000
    int*   csr_src= (int*)(ws + 35202880);                    //  3,400,000
    int*   bhist_blk = (int*)(ws + 38602880);                 //    ~81,536
    // total ~38.7 MB

    hipMemsetAsync(done, 0, sizeof(int), stream);

    bucket_hist_scan_kernel<<<NBLK, 256, 0, stream>>>(
        ei, E0, E, bhist_blk, done, bbase, bcursor, rowptr);
    bin_kernel<<<NBLK, 256, 0, stream>>>(ei, E0, E, bcursor, ebuf, bhist_blk);
    build_kernel<<<NB, 256, 0, stream>>>(ebuf, bbase, rowptr, csr_src);

    // layer 1: h1b = bf16(x @ W1^T), fused a_src1/a_dst1 (B-stationary GEMM)
    gemm1_att_kernel<<<(N + 63) / 64, 256, 0, stream>>>(
        x, W1, att_src1, att_dst1, h1b, a_src1, a_dst1, N);
    agg1_kernel<<<(N + 3) / 4, 256, 0, stream>>>(h1b, a_src1, a_dst1, rowptr, csr_src, b1, zb, N);

    // layer 2: h2b = bf16(zb @ W2^T), fused a_src2/a_dst2
    gemm_att_kernel<64, 48, 40, 128, 1, unsigned short>
        <<<(N + 63) / 64, 256, 0, stream>>>(zb, W2, att_src2, att_dst2,
                                            h2b, a_src2, a_dst2, N);
    agg2_kernel<<<(N + 3) / 4, 256, 0, stream>>>(h2b, a_src2, a_dst2, rowptr, csr_src, b2, out, N);
}

// Round 13
// 222.525 us; speedup vs baseline: 1.1368x; 1.0479x over previous
//
#include <hip/hip_runtime.h>
#include <hip/hip_bf16.h>
#include <cstdint>
#include <cstddef>

#define N_NODES 50000
#define NEG_SLOPE 0.2f
#define NB 196            // buckets of 256 nodes: (50000+255)/256
#define BIN_CHUNK 8192    // edges per block in hist/bin kernels (104 blocks)
#define SLICE_MAX 14336   // LDS slice capacity (mean ~4345, 3.3x headroom)

typedef float floatx4 __attribute__((ext_vector_type(4)));
typedef short shortx8 __attribute__((ext_vector_type(8)));

// ---- fp32 <-> bf16 helpers (RNE) --------------------------------------------
__device__ __forceinline__ unsigned short f2b(float f) {
    union { float f; unsigned u; } v; v.f = f;
    unsigned u = v.u;
    return (unsigned short)((u + 0x7FFFu + ((u >> 16) & 1u)) >> 16);
}
__device__ __forceinline__ float b2f(unsigned short b) {
    union { unsigned u; float f; } v; v.u = ((unsigned)b) << 16;
    return v.f;
}

// ---------------------------------------------------------------------------
// K1: per-block bucket histogram -> bhist_blk only (no global atomics,
// no memset needed; K2 reduces, K3 reuses per-block hists).
// ---------------------------------------------------------------------------
__global__ __launch_bounds__(256) void bucket_hist_kernel(
    const int* __restrict__ ei, int E0, int E, int* __restrict__ bhist_blk) {
    __shared__ int h[NB];
    int t = threadIdx.x;
    for (int i = t; i < NB; i += 256) h[i] = 0;
    __syncthreads();
    int base = blockIdx.x * BIN_CHUNK;
    int end = min(base + BIN_CHUNK, E);
    for (int e = base + t; e < end; e += 256) {
        int d = (e < E0) ? ei[E0 + e] : (e - E0);
        atomicAdd(&h[d >> 8], 1);
    }
    __syncthreads();
    for (int i = t; i < NB; i += 256)
        bhist_blk[blockIdx.x * NB + i] = h[i];
}

// K2: 1 block: 16-way-batched reduction over bhist_blk (104 blocks) -> scan
// -> bbase[NB+1], bcursor, rowptr[N]=E. Same-stream kernel boundary
// guarantees bhist_blk visibility (no fences needed).
__global__ __launch_bounds__(256) void bucket_scan_kernel(
    const int* __restrict__ bhist_blk, int nblk, int* __restrict__ bbase,
    int* __restrict__ bcursor, int* __restrict__ rowptr, int E) {
    __shared__ int buf[256];
    int t = threadIdx.x;
    int v = 0;
    if (t < NB) {
        int blk = 0;
        for (; blk + 16 <= nblk; blk += 16) {
            int tmp[16];
#pragma unroll
            for (int j = 0; j < 16; j++)
                tmp[j] = bhist_blk[(blk + j) * NB + t];
#pragma unroll
            for (int j = 0; j < 16; j++) v += tmp[j];
        }
        for (; blk < nblk; blk++) v += bhist_blk[blk * NB + t];
    }
    int x = v;
    for (int off = 1; off < 256; off <<= 1) {
        buf[t] = x; __syncthreads();
        int y = (t >= off) ? buf[t - off] : 0;
        __syncthreads();
        x += y;
    }
    if (t < NB) {
        bbase[t] = x - v;      // exclusive
        bcursor[t] = x - v;
    }
    if (t == NB - 1) bbase[NB] = x;
    if (t == 0) rowptr[N_NODES] = E;
}

// K3: bin edges into bucket regions, packed src|(dst&255)<<16, burst writes.
// Local histogram comes pre-computed from K1 (bhist_blk) — no pass 1.
__global__ __launch_bounds__(256) void bin_kernel(
    const int* __restrict__ ei, int E0, int E,
    int* __restrict__ bcursor, unsigned int* __restrict__ ebuf,
    const int* __restrict__ bhist_blk) {
    __shared__ int h[NB];
    __shared__ int gbase[NB];
    int t = threadIdx.x;
    for (int i = t; i < NB; i += 256) {
        int c = bhist_blk[blockIdx.x * NB + i];
        gbase[i] = c ? atomicAdd(&bcursor[i], c) : 0;
        h[i] = 0;  // local cursor
    }
    __syncthreads();
    int base = blockIdx.x * BIN_CHUNK;
    int end = min(base + BIN_CHUNK, E);
    for (int e = base + t; e < end; e += 256) {
        int s, d;
        if (e < E0) { s = ei[e]; d = ei[E0 + e]; }
        else        { s = e - E0; d = e - E0; }
        int b = d >> 8;
        int off = atomicAdd(&h[b], 1);
        ebuf[gbase[b] + off] = (unsigned)s | ((unsigned)(d & 255) << 16);
    }
}

// K4: one block per bucket: local deg-hist -> rowptr, LDS-staged CSR slice,
// fully-coalesced slice write.
__global__ __launch_bounds__(256) void build_kernel(
    const unsigned int* __restrict__ ebuf, const int* __restrict__ bbase,
    int* __restrict__ rowptr, int* __restrict__ csr_src) {
    __shared__ int h[256];
    __shared__ int lrp[257];
    __shared__ int stag[SLICE_MAX];
    int b = blockIdx.x, t = threadIdx.x;
    int e0 = bbase[b], e1 = bbase[b + 1];
    int cnt = e1 - e0;
    int n0 = b << 8;
    h[t] = 0;
    __syncthreads();
    for (int i = t; i < cnt; i += 256)
        atomicAdd(&h[ebuf[e0 + i] >> 16], 1);
    __syncthreads();
    int v = h[t], x = v;
    __shared__ int buf[256];
    for (int off = 1; off < 256; off <<= 1) {
        buf[t] = x; __syncthreads();
        int y = (t >= off) ? buf[t - off] : 0;
        __syncthreads();
        x += y;
    }
    lrp[t] = x - v;
    if (t == 255) lrp[256] = x;
    h[t] = 0;
    __syncthreads();
    int n = n0 + t;
    if (n < N_NODES) rowptr[n] = e0 + lrp[t];
    for (int i = t; i < cnt; i += 256) {
        unsigned int v2 = ebuf[e0 + i];
        int dloc = v2 >> 16;
        int off = atomicAdd(&h[dloc], 1);
        stag[lrp[dloc] + off] = (int)(v2 & 0xFFFFu);
    }
    __syncthreads();
    for (int i = t; i < cnt; i += 256) csr_src[e0 + i] = stag[i];
}

// ---------------------------------------------------------------------------
// bf16 MFMA GEMM + fused attention-coefficient epilogue (round-6 verified,
// 221.4us config). Register-batched staging + 1-deep cross-K prefetch.
// ---------------------------------------------------------------------------
template <int BM, int BN, int NREAL, int KK, int HEADS, typename InT>
__global__ __launch_bounds__(256) void gemm_att_kernel(
    const InT* __restrict__ A, const float* __restrict__ B,
    const float* __restrict__ att_src, const float* __restrict__ att_dst,
    unsigned short* __restrict__ Cb, float* __restrict__ a_src,
    float* __restrict__ a_dst, int M) {
    const int BK = 64, LDK = 72;
    const int NT = BN / 16;
    const int MT = BM / 64;            // m-tiles per wave
    const int NKI = KK / BK;
    const int LDC = NREAL + 8;
    const int NAf = BM * 16 / 256;     // float4 A-loads per thread (fp32 in)
    const int NAs = BM * 8 / 256;      // shortx8 A-loads per thread (bf16 in)
    const int NBv = BN * 16 / 256;     // float4 B-loads per thread
    constexpr int SMEM = ((BM + BN) * LDK > BM * LDC) ? (BM + BN) * LDK : BM * LDC;
    __shared__ unsigned short smem[SMEM];
    unsigned short* As = smem;
    unsigned short* Bs = smem + BM * LDK;
    const int t = threadIdx.x;
    const int wave = t >> 6, lane = t & 63;
    const int lrow = lane & 15, lkg = lane >> 4;
    const int bm = blockIdx.x * BM;

    floatx4 acc[MT][NT] = {};

    float4 avf[(sizeof(InT) == 4) ? NAf : 1];
    shortx8 avs[(sizeof(InT) == 2) ? NAs : 1];
    float4 bv[NBv];

    // ---- load first K-tile into regs (all loads issue back-to-back) ----
    {
        const int k0 = 0;
        if constexpr (sizeof(InT) == 4) {
#pragma unroll
            for (int q = 0; q < NAf; q++) {
                int i = t + q * 256;
                int r = i >> 4, c4 = (i & 15) << 2;
                int gr = bm + r;
                avf[q] = (gr < M) ? *(const float4*)&A[(size_t)gr * KK + k0 + c4]
                                  : make_float4(0.f, 0.f, 0.f, 0.f);
            }
        } else {
#pragma unroll
            for (int q = 0; q < NAs; q++) {
                int i = t + q * 256;
                int r = i >> 3, c8 = (i & 7) << 3;
                int gr = bm + r;
                shortx8 z = {};
                avs[q] = (gr < M) ? *(const shortx8*)&A[(size_t)gr * KK + k0 + c8] : z;
            }
        }
#pragma unroll
        for (int q = 0; q < NBv; q++) {
            int i = t + q * 256;
            int r = i >> 4, c4 = (i & 15) << 2;
            bv[q] = (r < NREAL) ? *(const float4*)&B[(size_t)r * KK + k0 + c4]
                                : make_float4(0.f, 0.f, 0.f, 0.f);
        }
    }

    for (int ki = 0; ki < NKI; ki++) {
        __syncthreads();
        // ---- regs -> LDS (convert fp32->bf16 here) ----
        if constexpr (sizeof(InT) == 4) {
#pragma unroll
            for (int q = 0; q < NAf; q++) {
                int i = t + q * 256;
                int r = i >> 4, c4 = (i & 15) << 2;
                int o = r * LDK + c4;
                float4 v = avf[q];
                As[o] = f2b(v.x); As[o + 1] = f2b(v.y);
                As[o + 2] = f2b(v.z); As[o + 3] = f2b(v.w);
            }
        } else {
#pragma unroll
            for (int q = 0; q < NAs; q++) {
                int i = t + q * 256;
                int r = i >> 3, c8 = (i & 7) << 3;
                *(shortx8*)&As[r * LDK + c8] = avs[q];
            }
        }
#pragma unroll
        for (int q = 0; q < NBv; q++) {
            int i = t + q * 256;
            int r = i >> 4, c4 = (i & 15) << 2;
            int o = r * LDK + c4;
            float4 v = bv[q];
            Bs[o] = f2b(v.x); Bs[o + 1] = f2b(v.y);
            Bs[o + 2] = f2b(v.z); Bs[o + 3] = f2b(v.w);
        }
        // ---- prefetch next K-tile (overlaps MFMA below) ----
        if (ki + 1 < NKI) {
            const int k0 = (ki + 1) * BK;
            if constexpr (sizeof(InT) == 4) {
#pragma unroll
                for (int q = 0; q < NAf; q++) {
                    int i = t + q * 256;
                    int r = i >> 4, c4 = (i & 15) << 2;
                    int gr = bm + r;
                    avf[q] = (gr < M) ? *(const float4*)&A[(size_t)gr * KK + k0 + c4]
                                      : make_float4(0.f, 0.f, 0.f, 0.f);
                }
            } else {
#pragma unroll
                for (int q = 0; q < NAs; q++) {
                    int i = t + q * 256;
                    int r = i >> 3, c8 = (i & 7) << 3;
                    int gr = bm + r;
                    shortx8 z = {};
                    avs[q] = (gr < M) ? *(const shortx8*)&A[(size_t)gr * KK + k0 + c8] : z;
                }
            }
#pragma unroll
            for (int q = 0; q < NBv; q++) {
                int i = t + q * 256;
                int r = i >> 4, c4 = (i & 15) << 2;
                bv[q] = (r < NREAL) ? *(const float4*)&B[(size_t)r * KK + k0 + c4]
                                    : make_float4(0.f, 0.f, 0.f, 0.f);
            }
        }
        __syncthreads();
        // ---- MFMA phase ----
        for (int ks = 0; ks < BK; ks += 32) {
            int kc = ks + lkg * 8;
#pragma unroll
            for (int mt = 0; mt < MT; mt++) {
                int row = wave * (MT * 16) + mt * 16 + lrow;
                shortx8 a = *(const shortx8*)&As[row * LDK + kc];
#pragma unroll
                for (int nt = 0; nt < NT; nt++) {
                    shortx8 b = *(const shortx8*)&Bs[(nt * 16 + lrow) * LDK + kc];
                    acc[mt][nt] = __builtin_amdgcn_mfma_f32_16x16x32_bf16(a, b, acc[mt][nt], 0, 0, 0);
                }
            }
        }
    }

    // ---- epilogue: C tile -> LDS (bf16) ----
    __syncthreads();
    unsigned short* Cs = smem;
#pragma unroll
    for (int mt = 0; mt < MT; mt++)
#pragma unroll
        for (int nt = 0; nt < NT; nt++)
#pragma unroll
            for (int r = 0; r < 4; r++) {
                int row = wave * (MT * 16) + mt * 16 + lkg * 4 + r;
                int col = nt * 16 + lrow;
                if (col < NREAL) Cs[row * LDC + col] = f2b(acc[mt][nt][r]);
            }
    __syncthreads();

    const int NCH = NREAL / 8;
    for (int i = t; i < BM * NCH; i += 256) {
        int row = i / NCH, ch = i - row * NCH;
        if (bm + row < M)
            *(shortx8*)&Cb[(size_t)(bm + row) * NREAL + ch * 8] =
                *(const shortx8*)&Cs[row * LDC + ch * 8];
    }

    const int D = NREAL / HEADS;
    if (t < 2 * BM) {
        int row = t >> 1, which = t & 1;
        if (bm + row < M) {
            const float* av = which ? att_dst : att_src;
            float hs[HEADS];
#pragma unroll
            for (int h = 0; h < HEADS; h++) hs[h] = 0.f;
#pragma unroll
            for (int c = 0; c < NCH; c++) {
                float4 p = *(const float4*)&av[c * 8];
                float4 q = *(const float4*)&av[c * 8 + 4];
                shortx8 cv = *(const shortx8*)&Cs[row * LDC + c * 8];
                float s = b2f((unsigned short)cv[0]) * p.x
                        + b2f((unsigned short)cv[1]) * p.y
                        + b2f((unsigned short)cv[2]) * p.z
                        + b2f((unsigned short)cv[3]) * p.w
                        + b2f((unsigned short)cv[4]) * q.x
                        + b2f((unsigned short)cv[5]) * q.y
                        + b2f((unsigned short)cv[6]) * q.z
                        + b2f((unsigned short)cv[7]) * q.w;
                hs[(c * 8) / D] += s;
            }
            float* outp = which ? a_dst : a_src;
#pragma unroll
            for (int h = 0; h < HEADS; h++)
                outp[(size_t)(bm + row) * HEADS + h] = hs[h];
        }
    }
}

// ---------------------------------------------------------------------------
// Aggregation layer 1: one WAVE per node. dwordx4 gather (4 edges per
// wave-instruction) + 2-stage software pipeline across 16-edge chunks.
// ---------------------------------------------------------------------------
__global__ __launch_bounds__(256) void agg1_kernel(
    const unsigned short* __restrict__ h1b, const float* __restrict__ a_src,
    const float* __restrict__ a_dst, const int* __restrict__ rowptr,
    const int* __restrict__ csr_src, const float* __restrict__ b1,
    unsigned short* __restrict__ zb, int N) {
    int wave = threadIdx.x >> 6, lane = threadIdx.x & 63;
    int n = blockIdx.x * 4 + wave;
    if (n >= N) return;
    int eg = lane >> 4;        // edge-slot group 0..3
    int fpos = lane & 15;      // feature block: feats fpos*8 .. fpos*8+7
    int hd = fpos >> 2;        // head of this feature block
    int lidx = lane >> 2;      // edge slot 0..15 in coeff phase
    int lh = lane & 3;         // head in coeff phase
    float adn = a_dst[n * 4 + lh];
    int beg = rowptr[n], deg = rowptr[n + 1] - beg;

    float acc[8] = {0.f, 0.f, 0.f, 0.f, 0.f, 0.f, 0.f, 0.f};
    float den = 0.f;

    // prologue: coeff inputs for chunk 0
    int s_e = (lidx < deg) ? csr_src[beg + lidx] : 0;
    float asv = a_src[(s_e << 2) + lh];

    for (int c0 = 0; c0 < deg; c0 += 16) {
        float l = asv + adn;
        l = l > 0.f ? l : NEG_SLOPE * l;
        float w_e = (c0 + lidx < deg) ? __expf(l) : 0.f;  // zero-pad dead edges
        int cnt = min(16, deg - c0);
        int s4[4]; float w4[4]; shortx8 v4[4];
#pragma unroll
        for (int q = 0; q < 4; q++) {
            int el = (q << 2) + eg;
            s4[q] = __shfl(s_e, el << 2);
            w4[q] = __shfl(w_e, (el << 2) + hd);
        }
#pragma unroll
        for (int q = 0; q < 4; q++) {
            if (q * 4 < cnt)
                v4[q] = *(const shortx8*)&h1b[(size_t)s4[q] * 128 + fpos * 8];
        }
        // prefetch next chunk's coeff inputs (overlaps gather latency)
        int nidx = c0 + 16 + lidx;
        int s_n = (nidx < deg) ? csr_src[beg + nidx] : 0;
        float asn = a_src[(s_n << 2) + lh];
#pragma unroll
        for (int q = 0; q < 4; q++) {
            if (q * 4 < cnt) {
                float w = w4[q];
                den += w;
#pragma unroll
                for (int j = 0; j < 8; j++)
                    acc[j] += w * b2f((unsigned short)v4[q][j]);
            }
        }
        s_e = s_n; asv = asn;
    }
#pragma unroll
    for (int j = 0; j < 8; j++) {
        acc[j] += __shfl_xor(acc[j], 16);
        acc[j] += __shfl_xor(acc[j], 32);
    }
    den += __shfl_xor(den, 16);
    den += __shfl_xor(den, 32);
    if (lane < 16) {
        float inv = 1.f / den;
        float4 bb0 = *(const float4*)&b1[fpos * 8];
        float4 bb1 = *(const float4*)&b1[fpos * 8 + 4];
        shortx8 r;
        r[0] = (short)f2b(fmaxf(acc[0] * inv + bb0.x, 0.f));
        r[1] = (short)f2b(fmaxf(acc[1] * inv + bb0.y, 0.f));
        r[2] = (short)f2b(fmaxf(acc[2] * inv + bb0.z, 0.f));
        r[3] = (short)f2b(fmaxf(acc[3] * inv + bb0.w, 0.f));
        r[4] = (short)f2b(fmaxf(acc[4] * inv + bb1.x, 0.f));
        r[5] = (short)f2b(fmaxf(acc[5] * inv + bb1.y, 0.f));
        r[6] = (short)f2b(fmaxf(acc[6] * inv + bb1.z, 0.f));
        r[7] = (short)f2b(fmaxf(acc[7] * inv + bb1.w, 0.f));
        *(shortx8*)&zb[(size_t)n * 128 + fpos * 8] = r;
    }
}

// ---------------------------------------------------------------------------
// Aggregation layer 2: one wave per node, H=1, D=40 (80B rows). 3 edges per
// wave-instruction (20 lanes x ushort2), coeff phase covers 48 edges.
// ---------------------------------------------------------------------------
__global__ __launch_bounds__(256) void agg2_kernel(
    const unsigned short* __restrict__ h2b, const float* __restrict__ a_src,
    const float* __restrict__ a_dst, const int* __restrict__ rowptr,
    const int* __restrict__ csr_src, const float* __restrict__ b2,
    float* __restrict__ out, int N) {
    int wave = threadIdx.x >> 6, lane = threadIdx.x & 63;
    int n = blockIdx.x * 4 + wave;
    if (n >= N) return;
    int eg = (lane >= 40) ? 2 : (lane >= 20 ? 1 : 0);  // edge-slot 0..2
    int fp = lane - eg * 20;                            // 0..19 (lanes 60-63: 20-23)
    bool act = fp < 20;
    float adn = a_dst[n];
    int beg = rowptr[n], deg = rowptr[n + 1] - beg;

    float2 acc = {0.f, 0.f};
    float den = 0.f;
    for (int c0 = 0; c0 < deg; c0 += 48) {
        int idx = c0 + lane;
        bool cv = (lane < 48) && (idx < deg);
        int s_e = cv ? csr_src[beg + idx] : 0;
        float l = a_src[s_e] + adn;
        l = l > 0.f ? l : NEG_SLOPE * l;
        float w_e = cv ? __expf(l) : 0.f;   // zero-pad dead edges
        int cnt = min(48, deg - c0);
#pragma unroll
        for (int qq = 0; qq < 4; qq++) {
            if (qq * 12 < cnt) {
                int s4[4]; float w4[4]; ushort2 v4[4];
#pragma unroll
                for (int q = 0; q < 4; q++) {
                    int el = qq * 12 + q * 3 + eg;
                    s4[q] = __shfl(s_e, el);
                    w4[q] = __shfl(w_e, el);
                }
#pragma unroll
                for (int q = 0; q < 4; q++) {
                    if (act)
                        v4[q] = *(const ushort2*)&h2b[(size_t)s4[q] * 40 + fp * 2];
                }
#pragma unroll
                for (int q = 0; q < 4; q++) {
                    float w = w4[q];
                    den += w;
                    if (act) {
                        acc.x += w * b2f(v4[q].x);
                        acc.y += w * b2f(v4[q].y);
                    }
                }
            }
        }
    }
    // combine 3 edge-slot partials: lanes {fp, fp+20, fp+40}
    float a1x = __shfl(acc.x, fp + 20), a2x = __shfl(acc.x, fp + 40);
    float a1y = __shfl(acc.y, fp + 20), a2y = __shfl(acc.y, fp + 40);
    float d1  = __shfl(den,  fp + 20), d2  = __shfl(den,  fp + 40);
    if (lane < 20) {
        float sx = acc.x + a1x + a2x;
        float sy = acc.y + a1y + a2y;
        float dtot = den + d1 + d2;
        float inv = 1.f / dtot;
        float2 bb = *(const float2*)&b2[fp * 2];
        float2 o;
        o.x = sx * inv + bb.x;
        o.y = sy * inv + bb.y;
        *(float2*)&out[(size_t)n * 40 + fp * 2] = o;
    }
}

// ---------------------------------------------------------------------------
extern "C" void kernel_launch(void* const* d_in, const int* in_sizes, int n_in,
                              void* d_out, int out_size, void* d_ws, size_t ws_size,
                              hipStream_t stream) {
    const float* x        = (const float*)d_in[0];
    const int*   ei       = (const int*)d_in[1];
    const float* W1       = (const float*)d_in[2];
    const float* att_src1 = (const float*)d_in[3];
    const float* att_dst1 = (const float*)d_in[4];
    const float* b1       = (const float*)d_in[5];
    const float* W2       = (const float*)d_in[6];
    const float* att_src2 = (const float*)d_in[7];
    const float* att_dst2 = (const float*)d_in[8];
    const float* b2       = (const float*)d_in[9];
    float* out = (float*)d_out;

    const int N  = N_NODES;
    const int E0 = in_sizes[1] / 2;
    const int E  = E0 + N;
    const int NBLK = (E + BIN_CHUNK - 1) / BIN_CHUNK;

    char* ws = (char*)d_ws;
    unsigned short* h1b = (unsigned short*)(ws + 0);          // 12,800,000
    unsigned short* zb  = (unsigned short*)(ws + 12800000);   // 12,800,000
    unsigned short* h2b = (unsigned short*)(ws + 25600000);   //  4,000,000
    float* a_src1 = (float*)(ws + 29600000);                  //    800,000
    float* a_dst1 = (float*)(ws + 30400000);                  //    800,000
    float* a_src2 = (float*)(ws + 31200000);                  //    200,000
    float* a_dst2 = (float*)(ws + 31400000);                  //    200,000
    int*   rowptr = (int*)(ws + 31600000);                    //    200,004
    int*   bbase  = (int*)(ws + 31801088);                    //        788
    int*   bcursor= (int*)(ws + 31801984);                    //        784
    unsigned int* ebuf = (unsigned int*)(ws + 31802880);      //  3,400,000
    int*   csr_src= (int*)(ws + 35202880);                    //  3,400,000
    int*   bhist_blk = (int*)(ws + 38602880);                 //    ~81,536
    // total ~38.7 MB

    bucket_hist_kernel<<<NBLK, 256, 0, stream>>>(ei, E0, E, bhist_blk);
    bucket_scan_kernel<<<1, 256, 0, stream>>>(bhist_blk, NBLK, bbase, bcursor, rowptr, E);
    bin_kernel<<<NBLK, 256, 0, stream>>>(ei, E0, E, bcursor, ebuf, bhist_blk);
    build_kernel<<<NB, 256, 0, stream>>>(ebuf, bbase, rowptr, csr_src);

    // layer 1: h1b = bf16(x @ W1^T), fused a_src1/a_dst1
    gemm_att_kernel<128, 128, 128, 256, 4, float>
        <<<(N + 127) / 128, 256, 0, stream>>>(x, W1, att_src1, att_dst1,
                                              h1b, a_src1, a_dst1, N);
    agg1_kernel<<<(N + 3) / 4, 256, 0, stream>>>(h1b, a_src1, a_dst1, rowptr, csr_src, b1, zb, N);

    // layer 2: h2b = bf16(zb @ W2^T), fused a_src2/a_dst2
    gemm_att_kernel<64, 48, 40, 128, 1, unsigned short>
        <<<(N + 63) / 64, 256, 0, stream>>>(zb, W2, att_src2, att_dst2,
                                            h2b, a_src2, a_dst2, N);
    agg2_kernel<<<(N + 3) / 4, 256, 0, stream>>>(h2b, a_src2, a_dst2, rowptr, csr_src, b2, out, N);
}